// Round 10
// baseline (832.518 us; speedup 1.0000x reference)
//
#include <hip/hip_runtime.h>
#include <math.h>

#define V 23
#define HH 256
#define BB 512
#define LL 1024
#define NOUT 46  // 2V

// Multiplicative inverses mod 23, packed 5 bits/entry into two u64 scalars.
constexpr unsigned long long packInv(int lo) {
    const int inv[23] = {0,1,12,8,6,14,4,10,3,18,7,21,2,16,5,20,13,19,9,17,15,11,22};
    unsigned long long t = 0;
    for (int i = 0; i < 12; ++i) {
        int idx = lo + i;
        if (idx < 23) t |= (unsigned long long)inv[idx] << (5 * i);
    }
    return t;
}
constexpr unsigned long long INV_T0 = packInv(0);
constexpr unsigned long long INV_T1 = packInv(12);

// VALU max-reduce step via DPP (no DS pipe)
#define DPPMAX(v, ctrl, rmask)                                                  \
    do {                                                                        \
        unsigned _t = (unsigned)__builtin_amdgcn_update_dpp(                    \
            (int)(v), (int)(v), (ctrl), (rmask), 0xF, false);                   \
        (v) = ((v) > _t) ? (v) : _t;                                            \
    } while (0)

// R9 post-mortem: DS-pipe ISSUE bound (~190 DS instr/CU-step ~= 1650cy ~=
// measured 1828cy/step; VALUBusy only 57%). 2/3 of DS traffic was the sV
// broadcast round-trip. This version deletes sV: each lane's v is broadcast
// via v_readlane_b32 (VALU pipe, SGPR operand feeds v_fma directly) --
// identical values/order => bit-identical numerics. DS per wave-step: ~7.
__global__ __launch_bounds__(256, 2)
void daf_kernel(const int* __restrict__ xtok,
                const float* __restrict__ W1,
                const float* __restrict__ b1,
                const float* __restrict__ W2,
                const float* __restrict__ b2,
                float* __restrict__ out)
{
    __shared__ float sW1[V * HH];          // 23552 B, h-update rows
    __shared__ float sW2T[NOUT * HH];      // 47104 B, TRANSPOSED: [col][row]
    __shared__ float sP[2][4][64];         // partials [parity][wave][lane]
    __shared__ unsigned char sTokB[LL];    // tokens as bytes
    __shared__ unsigned char sKB[LL];      // emitted symbols as bytes
    // total ~74.8 KB -> 2 blocks/CU

    const int tid = threadIdx.x;
    const int w   = tid >> 6;
    const int l   = tid & 63;
    const int b   = blockIdx.x;

    for (int i = tid; i < V * HH; i += 256) sW1[i] = W1[i];
    // transpose W2 into LDS: sW2T[col*256 + row] = W2[row*46 + col]
    for (int i = tid; i < NOUT * HH; i += 256) {
        const int col = i >> 8, row = i & 255;
        sW2T[i] = W2[row * NOUT + col];
    }
    for (int i = tid; i < LL; i += 256) sTokB[i] = (unsigned char)xtok[(size_t)b * LL + i];

    // Lane roles: lanes 0..22 own net[:V] (loc), lanes 32..54 own net[V:] (scale).
    const bool activeA = (l < V);
    const bool activeB = (l >= 32 && l < 32 + V);
    const bool active  = activeA || activeB;
    const int  col     = activeA ? l : (activeB ? (l - 32 + V) : 0);

    // h in double: 1024 sequential adds stay within 1 ulp of exact c@W1+b1.
    double h_pre = (double)b1[tid];
    const float bias = active ? b2[col] : 0.f;

    __syncthreads();   // sW2T ready

    // Pre-loop: pull this lane's W2 column-chunk (rows 64w..64w+63, col) from
    // LDS into 16 float4 registers. LDS provenance across a barrier defeats
    // rematerialization (R9: VGPR=88, resident). One-time conflicts are fine.
    float4 wr[16];
    {
        const float4* src = (const float4*)&sW2T[col * HH + 64 * w];
        #pragma unroll
        for (int q = 0; q < 16; ++q) wr[q] = src[q];
    }
    __syncthreads();   // remat fence: ds_reads can't sink past this

    for (int t = 0; t < LL; ++t) {
        const int tok = (int)sTokB[t];   // issued early; hidden under matvec

        // v = relu(h); broadcast via readlane, NOT LDS. readlane(v, i) ==
        // old sV[64w+i] (lane i of this wave) -> identical values and order.
        float v = fmaxf((float)h_pre, 0.f);
        const int vbits = __float_as_int(v);

        float a0 = 0.f, a1 = 0.f, a2 = 0.f, a3 = 0.f;
        #pragma unroll
        for (int q = 0; q < 16; ++q) {
            const float v0 = __int_as_float(__builtin_amdgcn_readlane(vbits, 4 * q + 0));
            const float v1 = __int_as_float(__builtin_amdgcn_readlane(vbits, 4 * q + 1));
            const float v2 = __int_as_float(__builtin_amdgcn_readlane(vbits, 4 * q + 2));
            const float v3 = __int_as_float(__builtin_amdgcn_readlane(vbits, 4 * q + 3));
            a0 = fmaf(v0, wr[q].x, a0);
            a1 = fmaf(v1, wr[q].y, a1);
            a2 = fmaf(v2, wr[q].z, a2);
            a3 = fmaf(v3, wr[q].w, a3);
        }
        const int p = t & 1;
        sP[p][w][l] = (a0 + a1) + (a2 + a3);   // stride-4B, conflict-free
        __syncthreads();   // the ONLY barrier per step

        // gather 4 wave-partials with conflict-free scalar reads
        float s0 = sP[p][0][l], s1 = sP[p][1][l];
        float s2 = sP[p][2][l], s3 = sP[p][3][l];
        float net = bias + ((s0 + s1) + (s2 + s3));   // same tree as R9

        int ib = __float_as_int(net);
        unsigned monoraw = (ib < 0) ? ~(unsigned)ib : ((unsigned)ib ^ 0x80000000u);
        const unsigned orig = active ? monoraw : 0u;  // lane's OWN key

        // dual 32-lane-half max-reduce on the VALU via DPP
        unsigned red = orig;
        DPPMAX(red, 0xB1,  0xF);  // quad_perm xor1
        DPPMAX(red, 0x4E,  0xF);  // quad_perm xor2
        DPPMAX(red, 0x141, 0xF);  // row_half_mirror
        DPPMAX(red, 0x140, 0xF);  // row_mirror
        DPPMAX(red, 0x142, 0xA);  // row_bcast15 into rows 1,3
        const unsigned sA = (unsigned)__builtin_amdgcn_readlane((int)red, 16);
        const unsigned sB = (unsigned)__builtin_amdgcn_readlane((int)red, 48);

        // winner = lowest lane whose ORIGINAL key equals its half's max
        // (lowest lane == lowest index == np first-max tie-break)
        const unsigned cmpv = (l < 32) ? sA : sB;
        const unsigned long long bal = __ballot(orig == cmpv);
        const int loc = __builtin_ctzll(bal & 0xFFFFFFFFull);
        const int sc  = __builtin_ctzll(bal >> 32);

        // inverse mod 23 from packed scalar table
        const unsigned long long tt = (sc < 12) ? INV_T0 : INV_T1;
        const int sh  = 5 * (sc - ((sc >= 12) ? 12 : 0));
        const int inv = (int)((tt >> sh) & 31);

        int m = tok - loc;
        m += (m >> 31) & V;            // (tok - loc) mod 23
        const int k = (m * inv) % V;   // compiler magic-mul for %23

        h_pre += (double)sW1[k * HH + tid];   // consecutive words, conflict-free
        if (tid == 0) sKB[t] = (unsigned char)k;
    }

    __syncthreads();
    float* outb = out + (size_t)b * LL * V;
    for (int t = tid; t < LL; t += 256)
        outb[t * V + (int)sKB[t]] = 1.0f;
}

extern "C" void kernel_launch(void* const* d_in, const int* in_sizes, int n_in,
                              void* d_out, int out_size, void* d_ws, size_t ws_size,
                              hipStream_t stream) {
    const int*   xtok = (const int*)d_in[0];
    const float* W1   = (const float*)d_in[1];
    const float* b1   = (const float*)d_in[2];
    const float* W2   = (const float*)d_in[3];
    const float* b2   = (const float*)d_in[4];
    float* out = (float*)d_out;

    // d_out poisoned 0xAA pre-launch: zero it, kernel scatters the 1.0s
    hipMemsetAsync(out, 0, (size_t)out_size * sizeof(float), stream);
    daf_kernel<<<BB, 256, 0, stream>>>(xtok, W1, b1, W2, b2, out);
}

// Round 11
// 809.661 us; speedup vs baseline: 1.0282x; 1.0282x over previous
//
#include <hip/hip_runtime.h>
#include <math.h>

#define V 23
#define HH 256
#define BB 512
#define LL 1024
#define NOUT 46  // 2V

// Multiplicative inverses mod 23, packed 5 bits/entry into two u64 scalars.
constexpr unsigned long long packInv(int lo) {
    const int inv[23] = {0,1,12,8,6,14,4,10,3,18,7,21,2,16,5,20,13,19,9,17,15,11,22};
    unsigned long long t = 0;
    for (int i = 0; i < 12; ++i) {
        int idx = lo + i;
        if (idx < 23) t |= (unsigned long long)inv[idx] << (5 * i);
    }
    return t;
}
constexpr unsigned long long INV_T0 = packInv(0);
constexpr unsigned long long INV_T1 = packInv(12);

// VALU max-reduce step via DPP (no DS pipe)
#define DPPMAX(v, ctrl, rmask)                                                  \
    do {                                                                        \
        unsigned _t = (unsigned)__builtin_amdgcn_update_dpp(                    \
            (int)(v), (int)(v), (ctrl), (rmask), 0xF, false);                   \
        (v) = ((v) > _t) ? (v) : _t;                                            \
    } while (0)

// R10 post-mortem: VMEM-fed (R6), DS-fed (R9) and VALU-fed (R10) matvecs all
// land at ~1830cy/step => none of those pipes binds. The invariant is the
// 4-wave barrier with 2 blocks sharing each SIMD. This version: 128 threads
// = 2 waves/block, 128 rows/wave (2 h-rows per thread). Still 2 blocks/CU
// (LDS ~72KB) but 4 waves/CU = 1 wave/SIMD: exclusive VALU issue, 2-wave
// barrier, single partner-read reduce (own partial stays in a register).
__global__ __launch_bounds__(128, 2)
void daf_kernel(const int* __restrict__ xtok,
                const float* __restrict__ W1,
                const float* __restrict__ b1,
                const float* __restrict__ W2,
                const float* __restrict__ b2,
                float* __restrict__ out)
{
    __shared__ float sW1[V * HH];          // 23552 B
    __shared__ float sW2T[NOUT * HH];      // 47104 B, transposed [col][row]
    __shared__ float sP[2][2][64];         // partials [parity][wave][lane]
    __shared__ unsigned char sTokB[LL];    // tokens as bytes
    __shared__ unsigned char sKB[LL];      // emitted symbols as bytes
    // total 73728 B -> 2 blocks/CU, 4 waves/CU, 1 wave/SIMD

    const int tid = threadIdx.x;
    const int w   = tid >> 6;              // wave 0..1
    const int l   = tid & 63;
    const int b   = blockIdx.x;

    for (int i = tid; i < V * HH; i += 128) sW1[i] = W1[i];
    for (int i = tid; i < NOUT * HH; i += 128) {   // sW2T[col*256+row]
        const int col = i >> 8, row = i & 255;
        sW2T[i] = W2[row * NOUT + col];
    }
    for (int i = tid; i < LL; i += 128) sTokB[i] = (unsigned char)xtok[(size_t)b * LL + i];

    // Lane roles (same as all passing rounds): lanes 0..22 own net[:V],
    // lanes 32..54 own net[V:].
    const bool activeA = (l < V);
    const bool activeB = (l >= 32 && l < 32 + V);
    const bool active  = activeA || activeB;
    const int  col     = activeA ? l : (activeB ? (l - 32 + V) : 0);

    // Each thread maintains TWO h rows: r0 = 128w + l, r1 = 128w + 64 + l.
    double h0 = (double)b1[128 * w + l];
    double h1 = (double)b1[128 * w + 64 + l];
    const float bias = active ? b2[col] : 0.f;

    __syncthreads();   // sW2T ready

    // Lane's W2 column-chunk: rows 128w..128w+127 of column col, 32 float4.
    // LDS provenance across a barrier defeats rematerialization (R9: VGPR=88).
    float4 wr[32];
    {
        const float4* src = (const float4*)&sW2T[col * HH + 128 * w];
        #pragma unroll
        for (int q = 0; q < 32; ++q) wr[q] = src[q];
    }
    __syncthreads();   // remat fence

    for (int t = 0; t < LL; ++t) {
        const int tok = (int)sTokB[t];

        // v = relu(h) for both owned rows; broadcast via readlane (VALU).
        // Rows 128w+i: i in 0..63 from vb0 lane i, i in 64..127 from vb1.
        const float v0f = fmaxf((float)h0, 0.f);
        const float v1f = fmaxf((float)h1, 0.f);
        const int vb0 = __float_as_int(v0f);
        const int vb1 = __float_as_int(v1f);

        float a0 = 0.f, a1 = 0.f, a2 = 0.f, a3 = 0.f;
        #pragma unroll
        for (int q = 0; q < 16; ++q) {   // rows 0..63 of the wave's 128
            const float x0 = __int_as_float(__builtin_amdgcn_readlane(vb0, 4 * q + 0));
            const float x1 = __int_as_float(__builtin_amdgcn_readlane(vb0, 4 * q + 1));
            const float x2 = __int_as_float(__builtin_amdgcn_readlane(vb0, 4 * q + 2));
            const float x3 = __int_as_float(__builtin_amdgcn_readlane(vb0, 4 * q + 3));
            a0 = fmaf(x0, wr[q].x, a0);
            a1 = fmaf(x1, wr[q].y, a1);
            a2 = fmaf(x2, wr[q].z, a2);
            a3 = fmaf(x3, wr[q].w, a3);
        }
        #pragma unroll
        for (int q = 16; q < 32; ++q) {  // rows 64..127
            const float x0 = __int_as_float(__builtin_amdgcn_readlane(vb1, 4 * (q - 16) + 0));
            const float x1 = __int_as_float(__builtin_amdgcn_readlane(vb1, 4 * (q - 16) + 1));
            const float x2 = __int_as_float(__builtin_amdgcn_readlane(vb1, 4 * (q - 16) + 2));
            const float x3 = __int_as_float(__builtin_amdgcn_readlane(vb1, 4 * (q - 16) + 3));
            a0 = fmaf(x0, wr[q].x, a0);
            a1 = fmaf(x1, wr[q].y, a1);
            a2 = fmaf(x2, wr[q].z, a2);
            a3 = fmaf(x3, wr[q].w, a3);
        }
        const float mine = (a0 + a1) + (a2 + a3);

        const int p = t & 1;
        sP[p][w][l] = mine;                // stride-4B, conflict-free
        __syncthreads();                   // 2-wave barrier (the only one)

        // partner partial from LDS; own stays in register. Fixed order
        // p_w0 + p_w1 -> bitwise-identical net in both waves.
        const float other = sP[p][1 - w][l];
        const float pw0 = (w == 0) ? mine : other;
        const float pw1 = (w == 0) ? other : mine;
        float net = bias + (pw0 + pw1);

        int ib = __float_as_int(net);
        unsigned monoraw = (ib < 0) ? ~(unsigned)ib : ((unsigned)ib ^ 0x80000000u);
        const unsigned orig = active ? monoraw : 0u;

        // dual 32-lane-half max-reduce on the VALU via DPP
        unsigned red = orig;
        DPPMAX(red, 0xB1,  0xF);  // quad_perm xor1
        DPPMAX(red, 0x4E,  0xF);  // quad_perm xor2
        DPPMAX(red, 0x141, 0xF);  // row_half_mirror
        DPPMAX(red, 0x140, 0xF);  // row_mirror
        DPPMAX(red, 0x142, 0xA);  // row_bcast15 into rows 1,3
        const unsigned sA = (unsigned)__builtin_amdgcn_readlane((int)red, 16);
        const unsigned sB = (unsigned)__builtin_amdgcn_readlane((int)red, 48);

        // winner = lowest lane whose ORIGINAL key equals its half's max
        const unsigned cmpv = (l < 32) ? sA : sB;
        const unsigned long long bal = __ballot(orig == cmpv);
        const int loc = __builtin_ctzll(bal & 0xFFFFFFFFull);
        const int sc  = __builtin_ctzll(bal >> 32);

        // inverse mod 23 from packed scalar table
        const unsigned long long tt = (sc < 12) ? INV_T0 : INV_T1;
        const int sh  = 5 * (sc - ((sc >= 12) ? 12 : 0));
        const int inv = (int)((tt >> sh) & 31);

        int m = tok - loc;
        m += (m >> 31) & V;            // (tok - loc) mod 23
        const int k = (m * inv) % V;   // magic-mul %23 (wave-uniform -> SALU)

        // h updates: consecutive-word LDS reads, conflict-free
        h0 += (double)sW1[k * HH + 128 * w + l];
        h1 += (double)sW1[k * HH + 128 * w + 64 + l];
        if (tid == 0) sKB[t] = (unsigned char)k;
    }

    __syncthreads();
    float* outb = out + (size_t)b * LL * V;
    for (int t = tid; t < LL; t += 128)
        outb[t * V + (int)sKB[t]] = 1.0f;
}

extern "C" void kernel_launch(void* const* d_in, const int* in_sizes, int n_in,
                              void* d_out, int out_size, void* d_ws, size_t ws_size,
                              hipStream_t stream) {
    const int*   xtok = (const int*)d_in[0];
    const float* W1   = (const float*)d_in[1];
    const float* b1   = (const float*)d_in[2];
    const float* W2   = (const float*)d_in[3];
    const float* b2   = (const float*)d_in[4];
    float* out = (float*)d_out;

    // d_out poisoned 0xAA pre-launch: zero it, kernel scatters the 1.0s
    hipMemsetAsync(out, 0, (size_t)out_size * sizeof(float), stream);
    daf_kernel<<<BB, 128, 0, stream>>>(xtok, W1, b1, W2, b2, out);
}